// Round 14
// baseline (179.559 us; speedup 1.0000x reference)
//
#include <hip/hip_runtime.h>
#include <hip/hip_bf16.h>
#include <cstdint>

// ---------- types / helpers ----------
typedef __attribute__((ext_vector_type(8))) short  short8;
typedef __attribute__((ext_vector_type(8))) __bf16 bf16x8;
typedef __attribute__((ext_vector_type(4))) float  floatx4;
typedef __attribute__((ext_vector_type(4))) float  f32x4;
typedef __attribute__((ext_vector_type(4))) short  short4v;

union Frag { short8 s; bf16x8 b; };

__device__ inline short f2bf(float f) {
    union { float f; unsigned u; } v; v.f = f;
    unsigned r = (v.u + 0x7fffu + ((v.u >> 16) & 1u)) >> 16;  // RNE
    return (short)r;
}
__device__ inline float elu(float x) { return x > 0.f ? x : __expf(x) - 1.f; }

__device__ inline short8 load8_f32_to_bf16(const float* __restrict__ p) {
    float4 f0 = ((const float4*)p)[0];
    float4 f1 = ((const float4*)p)[1];
    short8 r;
    r[0] = f2bf(f0.x); r[1] = f2bf(f0.y); r[2] = f2bf(f0.z); r[3] = f2bf(f0.w);
    r[4] = f2bf(f1.x); r[5] = f2bf(f1.y); r[6] = f2bf(f1.z); r[7] = f2bf(f1.w);
    return r;
}
__device__ inline float dot4(f32x4 a, f32x4 b) {
    return a.x * b.x + a.y * b.y + a.z * b.z + a.w * b.w;
}
__device__ inline f32x4 ntload4(const f32x4* __restrict__ p) {
    return __builtin_nontemporal_load(p);
}
__device__ inline float ntload1(const float* __restrict__ p) {
    return __builtin_nontemporal_load(p);
}
__device__ inline f32x4 relu4(f32x4 v) {
    f32x4 r;
    r.x = fmaxf(v.x, 0.f); r.y = fmaxf(v.y, 0.f);
    r.z = fmaxf(v.z, 0.f); r.w = fmaxf(v.w, 0.f);
    return r;
}

// ---------- constants ----------
#define B_SZ   4096
#define Z_DIM  256
#define H_DIM  1024
#define OUT_W  33
// option packing offsets (SIZES = [16384,64,4096,64,2048,32])
#define OFF_W1 0
#define OFF_B1 16384
#define OFF_W2 16448
#define OFF_B2 20544
#define OFF_W3 20608
#define OFF_B3 22656
#define OPT_W  22688

#define G_BLOCKS 256                // 128x128 tiles: (4096/128) x (1024/128)
#define CONV_BLOCKS 64
#define NB_H1 2048                  // W1-pass blocks (grid-stride)
#define NB_H2 1024                  // W2-pass blocks
#define NB_H3 1024                  // W3-pass blocks

// ---------- generalized MFMA gemm tile: block = (32*SM) x (32*SN) ----------
template<int KTOT, int SM, int SN, bool ACONV, bool BCONV, bool VEPI>
__device__ __forceinline__ void gemm_tile(
    const void* __restrict__ Av, const void* __restrict__ Bv,
    const float* __restrict__ bias, const float* __restrict__ w3,
    __hip_bfloat16* __restrict__ T, float* __restrict__ out,
    int bm, int bn, int tid)
{
    const int lane = tid & 63, wid = tid >> 6;
    const int wm = wid >> 1, wn = wid & 1;
    const int m_wave = bm * (32 * SM) + wm * (16 * SM);
    const int n_wave = bn * (32 * SN) + wn * (16 * SN);
    const int lr = lane & 15, lk = (lane >> 4) * 8;

    floatx4 acc[SM][SN] = {};
    for (int k0 = 0; k0 < KTOT; k0 += 32) {
        Frag a[SM], bb[SN];
#pragma unroll
        for (int sm = 0; sm < SM; ++sm) {
            const size_t off = (size_t)(m_wave + sm * 16 + lr) * KTOT + k0 + lk;
            if constexpr (ACONV) a[sm].s = load8_f32_to_bf16((const float*)Av + off);
            else                 a[sm].s = *(const short8*)((const ushort*)Av + off);
        }
#pragma unroll
        for (int sn = 0; sn < SN; ++sn) {
            const size_t off = (size_t)(n_wave + sn * 16 + lr) * KTOT + k0 + lk;
            if constexpr (BCONV) bb[sn].s = load8_f32_to_bf16((const float*)Bv + off);
            else                 bb[sn].s = *(const short8*)((const ushort*)Bv + off);
        }
#pragma unroll
        for (int sm = 0; sm < SM; ++sm)
#pragma unroll
            for (int sn = 0; sn < SN; ++sn)
                acc[sm][sn] = __builtin_amdgcn_mfma_f32_16x16x32_bf16(
                    a[sm].b, bb[sn].b, acc[sm][sn], 0, 0, 0);
    }

    if constexpr (VEPI) {
        float bias_v[SN], w3_v[SN];
#pragma unroll
        for (int sn = 0; sn < SN; ++sn) {
            const int n = n_wave + sn * 16 + lr;
            bias_v[sn] = bias[n];
            w3_v[sn]   = w3[n];
        }
#pragma unroll
        for (int sm = 0; sm < SM; ++sm) {
#pragma unroll
            for (int r = 0; r < 4; ++r) {
                float rowsum = 0.f;
#pragma unroll
                for (int sn = 0; sn < SN; ++sn)
                    rowsum += elu(acc[sm][sn][r] + bias_v[sn]) * w3_v[sn];
                rowsum += __shfl_xor(rowsum, 1);
                rowsum += __shfl_xor(rowsum, 2);
                rowsum += __shfl_xor(rowsum, 4);
                rowsum += __shfl_xor(rowsum, 8);
                if (lr == 0) {
                    const int m = m_wave + sm * 16 + (lane >> 4) * 4 + r;
                    atomicAdd(out + (size_t)m * OUT_W, rowsum);
                }
            }
        }
    } else {
#pragma unroll
        for (int sm = 0; sm < SM; ++sm)
#pragma unroll
            for (int sn = 0; sn < SN; ++sn) {
                const int n = n_wave + sn * 16 + lr;
                const float bv = bias[n];
#pragma unroll
                for (int r = 0; r < 4; ++r) {
                    const int m = m_wave + sm * 16 + (lane >> 4) * 4 + r;
                    T[(size_t)m * H_DIM + n] = __float2bfloat16(elu(acc[sm][sn][r] + bv));
                }
            }
    }
}

// ---------- W1 pass: grid-stride over 262144 rows (1KB each, contiguous) ----------
// At fixed t the chip reads a contiguous sliding window -> sequential DRAM walk.
// Stores PRE-RELU h1ws[R] = W1[b]row_r . z[b] + b1[b][r].
__device__ __forceinline__ void h1_pass(
    const float* __restrict__ z, const float* __restrict__ opt,
    float* __restrict__ h1ws, int hb, int tid)
{
    const int wid = tid >> 6, lane = tid & 63;
#pragma unroll
    for (int t = 0; t < 16; ++t) {
        const int Rb = t * 16384 + hb * 8 + wid * 2;
        const int b0 = (Rb) >> 6,     r0 = (Rb) & 63;
        const int b1i = (Rb + 1) >> 6, r1 = (Rb + 1) & 63;
        // issue all 4 loads up front
        f32x4 wv0 = ntload4((const f32x4*)(opt + (size_t)b0 * OPT_W + r0 * 256) + lane);
        f32x4 wv1 = ntload4((const f32x4*)(opt + (size_t)b1i * OPT_W + r1 * 256) + lane);
        f32x4 zv0 = *((const f32x4*)(z + (size_t)b0 * Z_DIM) + lane);
        f32x4 zv1 = *((const f32x4*)(z + (size_t)b1i * Z_DIM) + lane);

        float p0 = dot4(wv0, zv0);
        float p1 = dot4(wv1, zv1);
        p0 += __shfl_xor(p0, 1);  p1 += __shfl_xor(p1, 1);
        p0 += __shfl_xor(p0, 2);  p1 += __shfl_xor(p1, 2);
        p0 += __shfl_xor(p0, 4);  p1 += __shfl_xor(p1, 4);
        p0 += __shfl_xor(p0, 8);  p1 += __shfl_xor(p1, 8);
        p0 += __shfl_xor(p0, 16); p1 += __shfl_xor(p1, 16);
        p0 += __shfl_xor(p0, 32); p1 += __shfl_xor(p1, 32);
        if (lane == 0) {
            h1ws[Rb]     = p0 + ntload1(opt + (size_t)b0 * OPT_W + OFF_B1 + r0);
            h1ws[Rb + 1] = p1 + ntload1(opt + (size_t)b1i * OPT_W + OFF_B1 + r1);
        }
    }
}

// ---------- W2 pass: 65536 quad-rows (1KB = 4 rows of 64) ----------
// h2ws[b][r] = W2[b]row_r . relu(h1[b]) + b2[b][r]   (pre-relu stored)
__device__ __forceinline__ void h2_pass(
    const float* __restrict__ opt, const float* __restrict__ h1ws,
    float* __restrict__ h2ws, int hb, int tid)
{
    const int wid = tid >> 6, lane = tid & 63;
    const int l16 = lane & 15, lg = lane >> 4;
#pragma unroll
    for (int t = 0; t < 16; ++t) {
        const int R4 = t * 4096 + hb * 4 + wid;   // [0, 65536)
        const int b = R4 >> 4, q = R4 & 15;
        f32x4 wv = ntload4((const f32x4*)(opt + (size_t)b * OPT_W + OFF_W2 + q * 256) + lane);
        f32x4 hv = relu4(*(const f32x4*)(h1ws + (size_t)b * 64 + 4 * l16));
        float p = dot4(wv, hv);
        p += __shfl_xor(p, 1); p += __shfl_xor(p, 2);
        p += __shfl_xor(p, 4); p += __shfl_xor(p, 8);
        const int r = 4 * q + lg;
        if (l16 == 0)
            h2ws[(size_t)b * 64 + r] = p + ntload1(opt + (size_t)b * OPT_W + OFF_B2 + r);
    }
}

// ---------- W3 pass: 32768 quad-rows -> action ----------
__device__ __forceinline__ void h3_pass(
    const float* __restrict__ opt, const float* __restrict__ h2ws,
    float* __restrict__ out, int hb, int tid)
{
    const int wid = tid >> 6, lane = tid & 63;
    const int l16 = lane & 15, lg = lane >> 4;
#pragma unroll
    for (int t = 0; t < 8; ++t) {
        const int R4 = t * 4096 + hb * 4 + wid;   // [0, 32768)
        const int b = R4 >> 3, q = R4 & 7;
        f32x4 wv = ntload4((const f32x4*)(opt + (size_t)b * OPT_W + OFF_W3 + q * 256) + lane);
        f32x4 hv = relu4(*(const f32x4*)(h2ws + (size_t)b * 64 + 4 * l16));
        float p = dot4(wv, hv);
        p += __shfl_xor(p, 1); p += __shfl_xor(p, 2);
        p += __shfl_xor(p, 4); p += __shfl_xor(p, 8);
        const int r = 4 * q + lg;
        if (l16 == 0)
            out[(size_t)b * OUT_W + 1 + r] = p + ntload1(opt + (size_t)b * OPT_W + OFF_B3 + r);
    }
}

// ---------- kernel 1: gemm1 + w2conv + col0-init + W1 pass ----------
__global__ __launch_bounds__(256) void k1_kernel(
    const float* __restrict__ z, const float* __restrict__ opt,
    const float* __restrict__ w1, const float* __restrict__ b1,
    const float* __restrict__ w2, const float* __restrict__ b3,
    __hip_bfloat16* __restrict__ T1, __hip_bfloat16* __restrict__ w2bf,
    float* __restrict__ h1ws, float* __restrict__ out)
{
    const int blk = blockIdx.x, t = threadIdx.x;
    if (blk < G_BLOCKS) {
        const int j = (blk & 7) * 32 + (blk >> 3);   // XCD-chunked
        gemm_tile<Z_DIM, 4, 4, true, true, false>(z, w1, b1, nullptr, T1, nullptr,
                                                  j >> 3, j & 7, t);
    } else if (blk < G_BLOCKS + CONV_BLOCKS) {
        const int gtid = (blk - G_BLOCKS) * 256 + t;  // 0..16383
        if (gtid < B_SZ) out[(size_t)gtid * OUT_W] = b3[0];
#pragma unroll
        for (int i = 0; i < 16; ++i) {
            const int v = gtid + i * 16384;
            float4 f = ((const float4*)w2)[v];
            short4v s;
            s[0] = f2bf(f.x); s[1] = f2bf(f.y); s[2] = f2bf(f.z); s[3] = f2bf(f.w);
            ((short4v*)w2bf)[v] = s;
        }
    } else {
        h1_pass(z, opt, h1ws, blk - (G_BLOCKS + CONV_BLOCKS), t);
    }
}

// ---------- kernel 2: gemm2+value + W2 pass ----------
__global__ __launch_bounds__(256) void k2_kernel(
    const float* __restrict__ opt, const float* __restrict__ h1ws,
    const __hip_bfloat16* __restrict__ T1, const __hip_bfloat16* __restrict__ w2bf,
    const float* __restrict__ b2, const float* __restrict__ w3,
    float* __restrict__ h2ws, float* __restrict__ out)
{
    const int blk = blockIdx.x, t = threadIdx.x;
    if (blk < G_BLOCKS) {
        const int j = (blk & 7) * 32 + (blk >> 3);   // XCD-chunked
        gemm_tile<H_DIM, 4, 4, false, false, true>(T1, w2bf, b2, w3, nullptr, out,
                                                   j >> 3, j & 7, t);
    } else {
        h2_pass(opt, h1ws, h2ws, blk - G_BLOCKS, t);
    }
}

// ---------- kernel 3: W3 pass ----------
__global__ __launch_bounds__(256) void k3_kernel(
    const float* __restrict__ opt, const float* __restrict__ h2ws,
    float* __restrict__ out)
{
    h3_pass(opt, h2ws, out, blockIdx.x, threadIdx.x);
}

// ---------- launcher ----------
extern "C" void kernel_launch(void* const* d_in, const int* in_sizes, int n_in,
                              void* d_out, int out_size, void* d_ws, size_t ws_size,
                              hipStream_t stream)
{
    const float* z   = (const float*)d_in[0];
    const float* opt = (const float*)d_in[1];
    const float* w1  = (const float*)d_in[2];
    const float* b1  = (const float*)d_in[3];
    const float* w2  = (const float*)d_in[4];
    const float* b2  = (const float*)d_in[5];
    const float* w3  = (const float*)d_in[6];
    const float* b3  = (const float*)d_in[7];
    float* out = (float*)d_out;

    __hip_bfloat16* T1   = (__hip_bfloat16*)d_ws;                        // 8 MB
    __hip_bfloat16* w2bf = (__hip_bfloat16*)((char*)d_ws + 8u*1024*1024);   // 2 MB
    float*          h1ws = (float*)((char*)d_ws + 10u*1024*1024);        // 1 MB
    float*          h2ws = (float*)((char*)d_ws + 11u*1024*1024);        // 1 MB

    k1_kernel<<<dim3(G_BLOCKS + CONV_BLOCKS + NB_H1), dim3(256), 0, stream>>>(
        z, opt, w1, b1, w2, b3, T1, w2bf, h1ws, out);

    k2_kernel<<<dim3(G_BLOCKS + NB_H2), dim3(256), 0, stream>>>(
        opt, h1ws, T1, w2bf, b2, w3, h2ws, out);

    k3_kernel<<<dim3(NB_H3), dim3(256), 0, stream>>>(opt, h2ws, out);
}

// Round 16
// 111.065 us; speedup vs baseline: 1.6167x; 1.6167x over previous
//
#include <hip/hip_runtime.h>
#include <hip/hip_bf16.h>
#include <cstdint>

// ---------- types / helpers ----------
typedef __attribute__((ext_vector_type(8))) short  short8;
typedef __attribute__((ext_vector_type(8))) __bf16 bf16x8;
typedef __attribute__((ext_vector_type(4))) float  floatx4;
typedef __attribute__((ext_vector_type(4))) float  f32x4;
typedef __attribute__((ext_vector_type(4))) short  short4v;

union Frag { short8 s; bf16x8 b; };

__device__ inline short f2bf(float f) {
    union { float f; unsigned u; } v; v.f = f;
    unsigned r = (v.u + 0x7fffu + ((v.u >> 16) & 1u)) >> 16;  // RNE
    return (short)r;
}
__device__ inline float elu(float x) { return x > 0.f ? x : __expf(x) - 1.f; }

__device__ inline short8 load8_f32_to_bf16(const float* __restrict__ p) {
    float4 f0 = ((const float4*)p)[0];
    float4 f1 = ((const float4*)p)[1];
    short8 r;
    r[0] = f2bf(f0.x); r[1] = f2bf(f0.y); r[2] = f2bf(f0.z); r[3] = f2bf(f0.w);
    r[4] = f2bf(f1.x); r[5] = f2bf(f1.y); r[6] = f2bf(f1.z); r[7] = f2bf(f1.w);
    return r;
}
__device__ inline float dot4(f32x4 a, f32x4 b) {
    return a.x * b.x + a.y * b.y + a.z * b.z + a.w * b.w;
}
__device__ inline f32x4 relu4(f32x4 v) {
    f32x4 r;
    r.x = fmaxf(v.x, 0.f); r.y = fmaxf(v.y, 0.f);
    r.z = fmaxf(v.z, 0.f); r.w = fmaxf(v.w, 0.f);
    return r;
}

// ---------- constants ----------
#define B_SZ   4096
#define Z_DIM  256
#define H_DIM  1024
#define OUT_W  33
#define OPT_W  22688
// C-chunk internal float offsets (C = opt floats [16384,22688) of a sample row):
//   b1 @0, W2 @64, b2 @4160, W3 @4224, b3 @6272

#define G_BLOCKS 256       // 128x128 gemm tiles: 32 x 8
#define CONV_BLOCKS 64
#define HYP_BLOCKS 256     // persistent, 8 samples each per kernel
#define SPB 8              // samples per hyper block per kernel

// ---------- LDS map (77.5 KB -> 2 blocks/CU: 1 hyper + 1 gemm) ----------
#define LQ0   0            // 3 x 16KB W1-quarter ring
#define LQSZ  16384
#define LC    49152        // 28KB C chunk (25.2KB used + overshoot pad)
#define LZ    77824        // 1KB z row
#define LH1   78848        // 256B h1 (pre-bias)
#define LH2   79104        // 256B h2 (pre-bias)
#define LDS_TOTAL 79360

__device__ __forceinline__ void gload16(const void* g, void* l) {
    __builtin_amdgcn_global_load_lds((const uint32_t*)g, (uint32_t*)l, 16, 0, 0);
}
#define WAITVM(N) do { asm volatile("s_waitcnt vmcnt(" #N ") lgkmcnt(0)" ::: "memory"); \
                       __builtin_amdgcn_sched_barrier(0); } while (0)
#define WAITLGKM() do { asm volatile("s_waitcnt lgkmcnt(0)" ::: "memory"); \
                        __builtin_amdgcn_sched_barrier(0); } while (0)
#define SBAR() __builtin_amdgcn_s_barrier()

// ---------- staging (per wave; all counts fixed: Q=4, Z=1, C=7 instrs) ----------
__device__ __forceinline__ void stage_q(const float* __restrict__ orow, int q,
                                        char* smem, int buf, int w, int lane) {
    const float* gbase = orow + q * 4096;          // 16 W1 rows
    char* lbase = smem + LQ0 + buf * LQSZ;
#pragma unroll
    for (int i = 0; i < 4; ++i) {
        const int c = i * 4 + w;                   // 1KB chunk = one W1 row
        gload16(gbase + c * 256 + lane * 4, lbase + c * 1024);
    }
}
__device__ __forceinline__ void stage_z(const float* __restrict__ z, int smp,
                                        char* smem, int lane) {
    gload16(z + (size_t)smp * Z_DIM + lane * 4, smem + LZ);
}
__device__ __forceinline__ void stage_c(const float* __restrict__ orow,
                                        const float* __restrict__ optBase,
                                        const float* __restrict__ gLast,
                                        char* smem, int w, int lane) {
    const float* gbase = orow + 16384;
#pragma unroll
    for (int i = 0; i < 7; ++i) {
        const int c = i * 4 + w;
        const float* gp = gbase + c * 256 + lane * 4;
        gp = (gp > gLast) ? optBase : gp;          // clamp final-sample overshoot
        gload16(gp, smem + LC + c * 1024);
    }
}

// ---------- persistent DMA-streamed hypernet: 1 block/CU, SPB samples ----------
// Ring scheme: quarter q of sample s lives in buf (s+q)%3.
// vmcnt ledger (per wave, steady state): bar0 wait 8 -> {q0,z} landed;
// bar1 wait 11 -> {q1}; bar2 wait 11 -> {q2}; bar3 wait 5 -> {C,q3};
// bar4 wait 9 (no-op; C already drained). All LDS WARs are fenced by
// lgkmcnt(0)+s_barrier before the overwriting DMA issues.
__device__ __forceinline__ void hyper_block(
    const float* __restrict__ z, const float* __restrict__ opt,
    float* __restrict__ out, int baseSample, int tid, char* smem)
{
    const int w = tid >> 6, lane = tid & 63;
    const int l16 = lane & 15, lg = lane >> 4;
    const float* gLast = opt + (size_t)B_SZ * OPT_W - 4;
    float* h1raw = (float*)(smem + LH1);
    float* h2raw = (float*)(smem + LH2);

    // prologue: q0, Z, q1, q2 of sample 0 (bufs 0,1,2) -> 13 instrs/wave
    {
        const float* orow0 = opt + (size_t)baseSample * OPT_W;
        stage_q(orow0, 0, smem, 0, w, lane);
        stage_z(z, baseSample, smem, lane);
        stage_q(orow0, 1, smem, 1, w, lane);
        stage_q(orow0, 2, smem, 2, w, lane);
    }

    for (int s = 0; s < SPB; ++s) {
        const int smp = baseSample + s;
        const int snx = baseSample + ((s + 1) & (SPB - 1));   // wrap dummy at s=7
        const float* orow  = opt + (size_t)smp * OPT_W;
        const float* orowN = opt + (size_t)snx * OPT_W;
        const int m = s % 3;                                   // buf(q) = (s+q)%3

        // ---- bar0: q0_s and Z_s landed ----
        WAITVM(8); SBAR();
        stage_c(orow, opt, gLast, smem, w, lane);
        f32x4 zv[4];
#pragma unroll
        for (int p = 0; p < 4; ++p)
            zv[p] = *(const f32x4*)(smem + LZ + (p * 16 + l16) * 16);
        {   // quarter 0: rows 0-15  (buf m)
            const char* Qb = smem + LQ0 + m * LQSZ;
            float acc = 0.f;
#pragma unroll
            for (int p = 0; p < 4; ++p)
                acc += dot4(*(const f32x4*)(Qb + (w * 4 + lg) * 1024 + (p * 16 + l16) * 16), zv[p]);
            acc += __shfl_xor(acc, 1); acc += __shfl_xor(acc, 2);
            acc += __shfl_xor(acc, 4); acc += __shfl_xor(acc, 8);
            if (l16 == 0) h1raw[w * 4 + lg] = acc;
        }
        // ---- bar1: q1_s landed ----
        WAITVM(11); SBAR();
        stage_q(orow, 3, smem, m, w, lane);                    // q3_s -> buf (s+3)%3 == m
        {   // quarter 1: rows 16-31  (buf (m+1)%3)
            const char* Qb = smem + LQ0 + ((m + 1) % 3) * LQSZ;
            float acc = 0.f;
#pragma unroll
            for (int p = 0; p < 4; ++p)
                acc += dot4(*(const f32x4*)(Qb + (w * 4 + lg) * 1024 + (p * 16 + l16) * 16), zv[p]);
            acc += __shfl_xor(acc, 1); acc += __shfl_xor(acc, 2);
            acc += __shfl_xor(acc, 4); acc += __shfl_xor(acc, 8);
            if (l16 == 0) h1raw[16 + w * 4 + lg] = acc;
        }
        // ---- bar2: q2_s landed ----
        WAITVM(11); SBAR();
        stage_q(orowN, 0, smem, (m + 1) % 3, w, lane);         // q0_{s+1} -> buf (s+1)%3
        stage_z(z, snx, smem, lane);
        {   // quarter 2: rows 32-47  (buf (m+2)%3)
            const char* Qb = smem + LQ0 + ((m + 2) % 3) * LQSZ;
            float acc = 0.f;
#pragma unroll
            for (int p = 0; p < 4; ++p)
                acc += dot4(*(const f32x4*)(Qb + (w * 4 + lg) * 1024 + (p * 16 + l16) * 16), zv[p]);
            acc += __shfl_xor(acc, 1); acc += __shfl_xor(acc, 2);
            acc += __shfl_xor(acc, 4); acc += __shfl_xor(acc, 8);
            if (l16 == 0) h1raw[32 + w * 4 + lg] = acc;
        }
        // ---- bar3: C_s and q3_s landed ----
        WAITVM(5); SBAR();
        stage_q(orowN, 1, smem, (m + 2) % 3, w, lane);         // q1_{s+1} -> buf (s+2)%3
        {   // quarter 3: rows 48-63  (buf m)
            const char* Qb = smem + LQ0 + m * LQSZ;
            float acc = 0.f;
#pragma unroll
            for (int p = 0; p < 4; ++p)
                acc += dot4(*(const f32x4*)(Qb + (w * 4 + lg) * 1024 + (p * 16 + l16) * 16), zv[p]);
            acc += __shfl_xor(acc, 1); acc += __shfl_xor(acc, 2);
            acc += __shfl_xor(acc, 4); acc += __shfl_xor(acc, 8);
            if (l16 == 0) h1raw[48 + w * 4 + lg] = acc;
        }
        // ---- bar4: h1 visible (q3 reads of buf m complete -> safe to overwrite) ----
        WAITVM(9); SBAR();
        stage_q(orowN, 2, smem, m, w, lane);                   // FIX: q2_{s+1} -> buf (s+3)%3 == m
        const float* C = (const float*)(smem + LC);
        {   // layer 2: 64 rows, 16/wave
            f32x4 h1v = *(const f32x4*)(h1raw + 4 * l16);
            f32x4 b1v = *(const f32x4*)(C + 4 * l16);
            h1v = relu4(h1v + b1v);
#pragma unroll
            for (int j = 0; j < 4; ++j) {
                const int r = 16 * w + j * 4 + lg;
                f32x4 wv = *(const f32x4*)(C + 64 + r * 64 + 4 * l16);
                float p = dot4(wv, h1v);
                p += __shfl_xor(p, 1); p += __shfl_xor(p, 2);
                p += __shfl_xor(p, 4); p += __shfl_xor(p, 8);
                if (l16 == 0) h2raw[r] = p;
            }
        }
        // ---- bar5: h2 visible ----
        WAITLGKM(); SBAR();
        {   // layer 3: 32 rows, 8/wave -> actions
            f32x4 h2v = *(const f32x4*)(h2raw + 4 * l16);
            f32x4 b2v = *(const f32x4*)(C + 4160 + 4 * l16);
            h2v = relu4(h2v + b2v);
#pragma unroll
            for (int j = 0; j < 2; ++j) {
                const int r = 8 * w + j * 4 + lg;
                f32x4 wv = *(const f32x4*)(C + 4224 + r * 64 + 4 * l16);
                float p = dot4(wv, h2v);
                p += __shfl_xor(p, 1); p += __shfl_xor(p, 2);
                p += __shfl_xor(p, 4); p += __shfl_xor(p, 8);
                if (l16 == 0)
                    out[(size_t)smp * OUT_W + 1 + r] = p + C[6272 + r];
            }
        }
    }
}

// ---------- MFMA gemm tile (proven; unchanged) ----------
template<int KTOT, int SM, int SN, bool ACONV, bool BCONV, bool VEPI>
__device__ __forceinline__ void gemm_tile(
    const void* __restrict__ Av, const void* __restrict__ Bv,
    const float* __restrict__ bias, const float* __restrict__ w3,
    __hip_bfloat16* __restrict__ T, float* __restrict__ out,
    int bm, int bn, int tid)
{
    const int lane = tid & 63, wid = tid >> 6;
    const int wm = wid >> 1, wn = wid & 1;
    const int m_wave = bm * (32 * SM) + wm * (16 * SM);
    const int n_wave = bn * (32 * SN) + wn * (16 * SN);
    const int lr = lane & 15, lk = (lane >> 4) * 8;

    floatx4 acc[SM][SN] = {};
    for (int k0 = 0; k0 < KTOT; k0 += 32) {
        Frag a[SM], bb[SN];
#pragma unroll
        for (int sm = 0; sm < SM; ++sm) {
            const size_t off = (size_t)(m_wave + sm * 16 + lr) * KTOT + k0 + lk;
            if constexpr (ACONV) a[sm].s = load8_f32_to_bf16((const float*)Av + off);
            else                 a[sm].s = *(const short8*)((const ushort*)Av + off);
        }
#pragma unroll
        for (int sn = 0; sn < SN; ++sn) {
            const size_t off = (size_t)(n_wave + sn * 16 + lr) * KTOT + k0 + lk;
            if constexpr (BCONV) bb[sn].s = load8_f32_to_bf16((const float*)Bv + off);
            else                 bb[sn].s = *(const short8*)((const ushort*)Bv + off);
        }
#pragma unroll
        for (int sm = 0; sm < SM; ++sm)
#pragma unroll
            for (int sn = 0; sn < SN; ++sn)
                acc[sm][sn] = __builtin_amdgcn_mfma_f32_16x16x32_bf16(
                    a[sm].b, bb[sn].b, acc[sm][sn], 0, 0, 0);
    }

    if constexpr (VEPI) {
        float bias_v[SN], w3_v[SN];
#pragma unroll
        for (int sn = 0; sn < SN; ++sn) {
            const int n = n_wave + sn * 16 + lr;
            bias_v[sn] = bias[n];
            w3_v[sn]   = w3[n];
        }
#pragma unroll
        for (int sm = 0; sm < SM; ++sm) {
#pragma unroll
            for (int r = 0; r < 4; ++r) {
                float rowsum = 0.f;
#pragma unroll
                for (int sn = 0; sn < SN; ++sn)
                    rowsum += elu(acc[sm][sn][r] + bias_v[sn]) * w3_v[sn];
                rowsum += __shfl_xor(rowsum, 1);
                rowsum += __shfl_xor(rowsum, 2);
                rowsum += __shfl_xor(rowsum, 4);
                rowsum += __shfl_xor(rowsum, 8);
                if (lr == 0) {
                    const int mm = m_wave + sm * 16 + (lane >> 4) * 4 + r;
                    atomicAdd(out + (size_t)mm * OUT_W, rowsum);
                }
            }
        }
    } else {
#pragma unroll
        for (int sm = 0; sm < SM; ++sm)
#pragma unroll
            for (int sn = 0; sn < SN; ++sn) {
                const int n = n_wave + sn * 16 + lr;
                const float bv = bias[n];
#pragma unroll
                for (int r = 0; r < 4; ++r) {
                    const int mm = m_wave + sm * 16 + (lane >> 4) * 4 + r;
                    T[(size_t)mm * H_DIM + n] = __float2bfloat16(elu(acc[sm][sn][r] + bv));
                }
            }
    }
}

// ---------- kernel 1: hyper[0,2048) + gemm1 + w2conv + col0-init ----------
__global__ __launch_bounds__(256) void k1_kernel(
    const float* __restrict__ z, const float* __restrict__ opt,
    const float* __restrict__ w1, const float* __restrict__ b1,
    const float* __restrict__ w2, const float* __restrict__ b3,
    __hip_bfloat16* __restrict__ T1, __hip_bfloat16* __restrict__ w2bf,
    float* __restrict__ out)
{
    __shared__ __align__(16) char smem[LDS_TOTAL];
    const int blk = blockIdx.x, t = threadIdx.x;
    if (blk < HYP_BLOCKS) {
        hyper_block(z, opt, out, blk * SPB, t, smem);
    } else if (blk < HYP_BLOCKS + G_BLOCKS) {
        const int j0 = blk - HYP_BLOCKS;
        const int j = (j0 & 7) * 32 + (j0 >> 3);   // XCD-chunked
        gemm_tile<Z_DIM, 4, 4, true, true, false>(z, w1, b1, nullptr, T1, nullptr,
                                                  j >> 3, j & 7, t);
    } else {
        const int gtid = (blk - HYP_BLOCKS - G_BLOCKS) * 256 + t;  // 0..16383
        if (gtid < B_SZ) out[(size_t)gtid * OUT_W] = b3[0];
#pragma unroll
        for (int i = 0; i < 16; ++i) {
            const int v = gtid + i * 16384;
            float4 f = ((const float4*)w2)[v];
            short4v sv;
            sv[0] = f2bf(f.x); sv[1] = f2bf(f.y); sv[2] = f2bf(f.z); sv[3] = f2bf(f.w);
            ((short4v*)w2bf)[v] = sv;
        }
    }
}

// ---------- kernel 2: hyper[2048,4096) + gemm2+value ----------
__global__ __launch_bounds__(256) void k2_kernel(
    const float* __restrict__ z, const float* __restrict__ opt,
    const __hip_bfloat16* __restrict__ T1, const __hip_bfloat16* __restrict__ w2bf,
    const float* __restrict__ b2, const float* __restrict__ w3,
    float* __restrict__ out)
{
    __shared__ __align__(16) char smem[LDS_TOTAL];
    const int blk = blockIdx.x, t = threadIdx.x;
    if (blk < HYP_BLOCKS) {
        hyper_block(z, opt, out, 2048 + blk * SPB, t, smem);
    } else {
        const int j0 = blk - HYP_BLOCKS;
        const int j = (j0 & 7) * 32 + (j0 >> 3);   // XCD-chunked
        gemm_tile<H_DIM, 4, 4, false, false, true>(T1, w2bf, b2, w3, nullptr, out,
                                                   j >> 3, j & 7, t);
    }
}

// ---------- launcher ----------
extern "C" void kernel_launch(void* const* d_in, const int* in_sizes, int n_in,
                              void* d_out, int out_size, void* d_ws, size_t ws_size,
                              hipStream_t stream)
{
    const float* z   = (const float*)d_in[0];
    const float* opt = (const float*)d_in[1];
    const float* w1  = (const float*)d_in[2];
    const float* b1  = (const float*)d_in[3];
    const float* w2  = (const float*)d_in[4];
    const float* b2  = (const float*)d_in[5];
    const float* w3  = (const float*)d_in[6];
    const float* b3  = (const float*)d_in[7];
    float* out = (float*)d_out;

    __hip_bfloat16* T1   = (__hip_bfloat16*)d_ws;                          // 8 MB
    __hip_bfloat16* w2bf = (__hip_bfloat16*)((char*)d_ws + 8u * 1024 * 1024);  // 2 MB

    k1_kernel<<<dim3(HYP_BLOCKS + G_BLOCKS + CONV_BLOCKS), dim3(256), 0, stream>>>(
        z, opt, w1, b1, w2, b3, T1, w2bf, out);

    k2_kernel<<<dim3(HYP_BLOCKS + G_BLOCKS), dim3(256), 0, stream>>>(
        z, opt, T1, w2bf, b2, w3, out);
}